// Round 5
// baseline (436.954 us; speedup 1.0000x reference)
//
#include <hip/hip_runtime.h>
#include <hip/hip_cooperative_groups.h>
#include <stdint.h>

namespace cg = cooperative_groups;

#define M_DIM 4096
#define T_DIM 2048
#define N_OUT 2024
#define N_PAD 2048
#define WIN   25
#define K_DIM 4096

typedef float f32x4 __attribute__((ext_vector_type(4)));

__device__ __forceinline__ unsigned short f2bf(float x) {
  unsigned u = __float_as_uint(x);
  u += 0x7FFF + ((u >> 16) & 1);           // round-to-nearest-even
  return (unsigned short)(u >> 16);
}
__device__ __forceinline__ float bf2f(unsigned short h) {
  return __uint_as_float(((unsigned)h) << 16);
}

__device__ __forceinline__ void gl2lds16(const void* g, void* l) {
  // 16B-wide async global->LDS; HW dest = wave-uniform base + lane*16
  __builtin_amdgcn_global_load_lds(
      (const __attribute__((address_space(1))) unsigned int*)g,
      (__attribute__((address_space(3))) unsigned int*)l, 16, 0, 0);
}

// pack 4 floats -> 4 e4m3 bytes (one dword)
__device__ __forceinline__ int pk_fp8x4(float a, float b, float c, float d) {
  int w = __builtin_amdgcn_cvt_pk_fp8_f32(a, b, 0, false);
  w = __builtin_amdgcn_cvt_pk_fp8_f32(c, d, w, true);
  return w;
}

// ============================ PREP phase ============================
// 512 blocks x 512 threads, grid-strided. Same math as the R11 prep
// kernels (identical op order per output element -> identical numerics).
__device__ __forceinline__ void prep_body(int bid, int tid,
                                          const float* __restrict__ alphas,
                                          const float* __restrict__ ys,
                                          const float* __restrict__ repro,
                                          unsigned char* __restrict__ W8,
                                          unsigned char* __restrict__ BT8,
                                          unsigned short* __restrict__ Sbf,
                                          char* SMEM) {
  // ---- wcast: W8 = e4m3(sigmoid(alphas)), diag -> 0. 2M uint2 items. ----
  {
    int idx = bid * 512 + tid;                 // 262144 threads
#pragma unroll
    for (int itr = 0; itr < 8; ++itr) {
      size_t i8 = ((size_t)idx + (size_t)itr * 262144) * 8;
      const float4 v0 = *(const float4*)(alphas + i8);
      const float4 v1 = *(const float4*)(alphas + i8 + 4);
      int row = (int)(i8 >> 12);
      int col = (int)(i8 & 4095);
      float a[8] = {v0.x, v0.y, v0.z, v0.w, v1.x, v1.y, v1.z, v1.w};
      float w[8];
#pragma unroll
      for (int j = 0; j < 8; ++j)
        w[j] = (row == col + j) ? 0.f : 1.f / (1.f + __expf(-a[j]));
      int p0 = pk_fp8x4(w[0], w[1], w[2], w[3]);
      int p1 = pk_fp8x4(w[4], w[5], w[6], w[7]);
      *(uint2*)(W8 + i8) = uint2{(unsigned)p0, (unsigned)p1};
    }
  }

  // ---- conv: Sbf = bf16(softplus(conv(ys,repro))). wave = one row. ----
  {
    int m = bid * 8 + (tid >> 6);              // 512*8 = 4096 rows
    int lane = tid & 63;
    float r[WIN];
#pragma unroll
    for (int k = 0; k < WIN; ++k) r[k] = repro[m * WIN + k];
#pragma unroll
    for (int p = 0; p < 2; ++p) {
      int c0 = lane * 32 + p * 16;             // 16-aligned -> float4 chunks
      float y[16 + WIN - 1];                   // 40 taps window
#pragma unroll
      for (int ch = 0; ch < 10; ++ch) {        // 10 float4 chunks, 4-aligned
        int c = c0 + ch * 4;
        float4 v = (c + 3 < T_DIM) ? *(const float4*)(ys + (size_t)m * T_DIM + c)
                                   : float4{0.f, 0.f, 0.f, 0.f};
        y[ch * 4 + 0] = v.x; y[ch * 4 + 1] = v.y;
        y[ch * 4 + 2] = v.z; y[ch * 4 + 3] = v.w;
      }
      unsigned short ob[16];
#pragma unroll
      for (int j = 0; j < 16; ++j) {
        float z = 0.f;
#pragma unroll
        for (int k = 0; k < WIN; ++k) z += y[j + k] * r[k];
        float sp = fmaxf(z, 0.f) + log1pf(__expf(-fabsf(z)));
        int gj = c0 + j;
        ob[j] = (gj < N_OUT) ? f2bf(sp) : (unsigned short)0;
      }
      unsigned short* dst = Sbf + (size_t)m * N_PAD + c0;
      *(uint4*)dst = ((const uint4*)ob)[0];
      *(uint4*)(dst + 8) = ((const uint4*)ob)[1];
    }
  }

  // ---- transpose: BT8[n][k] = e4m3(ys[k][n+24]). 4 tiles/block. ----
  {
    int half = tid >> 8;                       // 0/1 : two tiles concurrently
    int st   = tid & 255;
    float (*t)[65] = (float (*)[65])(SMEM + half * 16640);
    int tx = st & 63;
    int ty = st >> 6;
#pragma unroll 1
    for (int it = 0; it < 2; ++it) {
      int b  = bid * 4 + it * 2 + half;        // 0..2047
      int n0 = (b & 31) * 64;
      int k0 = (b >> 5) * 64;
#pragma unroll
      for (int rr = 0; rr < 16; ++rr) {
        int kk = k0 + ty + rr * 4;
        int n = n0 + tx;
        t[ty + rr * 4][tx] = (n < N_OUT) ? ys[(size_t)kk * T_DIM + n + (WIN - 1)] : 0.f;
      }
      __syncthreads();
      int nl = st >> 2;
      int kc = (st & 3) * 16;
      unsigned wds[4];
#pragma unroll
      for (int w = 0; w < 4; ++w)
        wds[w] = (unsigned)pk_fp8x4(t[kc + 4 * w][nl], t[kc + 4 * w + 1][nl],
                                    t[kc + 4 * w + 2][nl], t[kc + 4 * w + 3][nl]);
      *(uint4*)(BT8 + (size_t)(n0 + nl) * K_DIM + k0 + kc) =
          uint4{wds[0], wds[1], wds[2], wds[3]};
      __syncthreads();
    }
  }
}

// ============================ GEMM phase ============================
// R9 body verbatim (proven 86.4 us): 8 waves, wave = 64x32 out, 4-buffer
// depth-3 counted vmcnt(6), XOR chunk swizzle, XCD-bijective block swizzle.
__device__ __forceinline__ void gemm_body(int bid, int tid,
                                          const unsigned char* __restrict__ W8,
                                          const unsigned char* __restrict__ BT8,
                                          const unsigned short* __restrict__ Sbf,
                                          const float* __restrict__ b0,
                                          const float* __restrict__ b1,
                                          float* __restrict__ out,
                                          char* SMEM) {
  unsigned char* lA = (unsigned char*)SMEM;            // 4 x 8 KB
  unsigned char* lB = (unsigned char*)SMEM + 32768;    // 4 x 8 KB
  const int wave = tid >> 6;          // 0..7
  const int lane = tid & 63;
  const int wm = wave >> 2;           // 0..1 : 64-row slice
  const int wn = wave & 3;            // 0..3 : 32-col slice
  const int m16  = lane & 15;
  const int quad = lane >> 4;

  // XCD-aware bijective swizzle (512%8==0)
  const int swz  = (bid & 7) * 64 + (bid >> 3);
  const int tileN = (swz & 15) * 128;
  const int tileM = (swz >> 4) * 128;

  const int key  = (m16 >> 1) & 3;
  const int sub  = (quad & 1) * 8;
  const int rowA = (wm * 64 + m16) * 64;
  const int rowB = (wn * 32 + m16) * 64;
  int hOf[2];
#pragma unroll
  for (int h = 0; h < 2; ++h)
    hOf[h] = (((2 * h + (quad >> 1)) ^ key) << 4) + sub;

  const int o = wave * 1024 + lane * 16;   // 0..8191
  const int r = o >> 6;                    // LDS row 0..127
  const int s = (o >> 4) & 3;              // LDS chunk slot
  const int q = s ^ ((r >> 1) & 3);        // logical (global) chunk
  const unsigned char* gA = W8  + (size_t)(tileM + r) * K_DIM + q * 16;
  const unsigned char* gB = BT8 + (size_t)(tileN + r) * K_DIM + q * 16;
  const int ldsOff = wave * 1024;          // wave-uniform base

  f32x4 acc[4][2];
#pragma unroll
  for (int i = 0; i < 4; ++i)
#pragma unroll
    for (int j = 0; j < 2; ++j) acc[i][j] = f32x4{0.f, 0.f, 0.f, 0.f};

  auto stage = [&](int buf, int kt_) {
    const size_t kb_ = (size_t)kt_ * 64;
    gl2lds16(gA + kb_, lA + buf * 8192 + ldsOff);
    gl2lds16(gB + kb_, lB + buf * 8192 + ldsOff);
  };
  auto compute = [&](int buf) {
#pragma unroll
    for (int h = 0; h < 2; ++h) {
      long long aF[4], bF[2];
#pragma unroll
      for (int i = 0; i < 4; ++i)
        aF[i] = *(const long long*)(lA + buf * 8192 + rowA + i * 1024 + hOf[h]);
#pragma unroll
      for (int j = 0; j < 2; ++j)
        bF[j] = *(const long long*)(lB + buf * 8192 + rowB + j * 1024 + hOf[h]);
#pragma unroll
      for (int i = 0; i < 4; ++i)
#pragma unroll
        for (int j = 0; j < 2; ++j)
          acc[i][j] = __builtin_amdgcn_mfma_f32_16x16x32_fp8_fp8(
              aF[i], bF[j], acc[i][j], 0, 0, 0);
    }
  };

  stage(0, 0);
  stage(1, 1);
  stage(2, 2);

#pragma unroll 1
  for (int kt = 0; kt < K_DIM / 64; kt += 4) {
    stage(3, kt + 3);
    asm volatile("s_waitcnt vmcnt(6)" ::: "memory");
    __builtin_amdgcn_s_barrier();
    asm volatile("" ::: "memory");
    compute(0);
    __builtin_amdgcn_s_barrier();
    asm volatile("" ::: "memory");

    if (kt + 4 < K_DIM / 64) {
      stage(0, kt + 4);
      asm volatile("s_waitcnt vmcnt(6)" ::: "memory");
    } else {
      asm volatile("s_waitcnt vmcnt(4)" ::: "memory");
    }
    __builtin_amdgcn_s_barrier();
    asm volatile("" ::: "memory");
    compute(1);
    __builtin_amdgcn_s_barrier();
    asm volatile("" ::: "memory");

    if (kt + 5 < K_DIM / 64) {
      stage(1, kt + 5);
      asm volatile("s_waitcnt vmcnt(6)" ::: "memory");
    } else {
      asm volatile("s_waitcnt vmcnt(2)" ::: "memory");
    }
    __builtin_amdgcn_s_barrier();
    asm volatile("" ::: "memory");
    compute(2);
    __builtin_amdgcn_s_barrier();
    asm volatile("" ::: "memory");

    if (kt + 6 < K_DIM / 64) {
      stage(2, kt + 6);
      asm volatile("s_waitcnt vmcnt(6)" ::: "memory");
    } else {
      asm volatile("s_waitcnt vmcnt(0)" ::: "memory");
    }
    __builtin_amdgcn_s_barrier();
    asm volatile("" ::: "memory");
    compute(3);
    __builtin_amdgcn_s_barrier();
    asm volatile("" ::: "memory");
  }

  // Epilogue: out[gm][gn] = softplus(b0+b1*(gn+25)) * (S[gm][gn] + C)
#pragma unroll
  for (int j = 0; j < 2; ++j) {
    int gn = tileN + wn * 32 + j * 16 + m16;
    if (gn >= N_OUT) continue;
    float tval = (float)(gn + WIN);
#pragma unroll
    for (int i = 0; i < 4; ++i) {
#pragma unroll
      for (int r2 = 0; r2 < 4; ++r2) {
        int gm = tileM + wm * 64 + i * 16 + quad * 4 + r2;
        float x = b0[gm] + b1[gm] * tval;
        float beta = fmaxf(x, 0.f) + log1pf(__expf(-fabsf(x)));
        float sv = bf2f(Sbf[(size_t)gm * N_PAD + gn]);
        out[(size_t)gm * N_OUT + gn] = beta * (sv + acc[i][j][r2]);
      }
    }
  }
}

// ---------- Fused cooperative kernel: prep -> grid.sync -> gemm ----------
// R12: total has been pinned at ~255 us across R0-R4 while k_gemm went
// 171->86: ~120+ us is inter-dispatch dead time that per-kernel tuning
// can't reach. One cooperative dispatch removes it. 512x512, LDS 64 KB ->
// exactly 2 blocks/CU co-resident (coop requirement). threadfence +
// grid.sync gives cross-XCD visibility of W8/BT8/Sbf (agent-scope release
// writes back L2).
__global__ __launch_bounds__(512, 4) void k_fused(const float* __restrict__ ys,
                                                  const float* __restrict__ alphas,
                                                  const float* __restrict__ repro,
                                                  const float* __restrict__ b0,
                                                  const float* __restrict__ b1,
                                                  unsigned char* __restrict__ W8,
                                                  unsigned char* __restrict__ BT8,
                                                  unsigned short* __restrict__ Sbf,
                                                  float* __restrict__ out) {
  __shared__ __align__(64) char SMEM[65536];
  const int bid = blockIdx.x;
  const int tid = threadIdx.x;
  prep_body(bid, tid, alphas, ys, repro, W8, BT8, Sbf, SMEM);
  __threadfence();
  cg::this_grid().sync();
  gemm_body(bid, tid, W8, BT8, Sbf, b0, b1, out, SMEM);
}

// Fallback pair (same bodies) if cooperative launch is rejected in capture.
__global__ __launch_bounds__(512, 4) void k_prep2(const float* __restrict__ ys,
                                                  const float* __restrict__ alphas,
                                                  const float* __restrict__ repro,
                                                  unsigned char* __restrict__ W8,
                                                  unsigned char* __restrict__ BT8,
                                                  unsigned short* __restrict__ Sbf) {
  __shared__ __align__(64) char SMEM[65536];
  prep_body(blockIdx.x, threadIdx.x, alphas, ys, repro, W8, BT8, Sbf, SMEM);
}
__global__ __launch_bounds__(512, 4) void k_gemm2(const unsigned char* __restrict__ W8,
                                                  const unsigned char* __restrict__ BT8,
                                                  const unsigned short* __restrict__ Sbf,
                                                  const float* __restrict__ b0,
                                                  const float* __restrict__ b1,
                                                  float* __restrict__ out) {
  __shared__ __align__(64) char SMEM[65536];
  gemm_body(blockIdx.x, threadIdx.x, W8, BT8, Sbf, b0, b1, out, SMEM);
}

extern "C" void kernel_launch(void* const* d_in, const int* in_sizes, int n_in,
                              void* d_out, int out_size, void* d_ws, size_t ws_size,
                              hipStream_t stream) {
  const float* ys     = (const float*)d_in[0];
  const float* alphas = (const float*)d_in[1];
  const float* repro  = (const float*)d_in[2];
  const float* b0     = (const float*)d_in[3];
  const float* b1     = (const float*)d_in[4];
  float* out = (float*)d_out;

  char* ws = (char*)d_ws;
  unsigned char*  W8  = (unsigned char*)ws;                                    // 16 MiB
  unsigned char*  BT8 = (unsigned char*)(ws + (size_t)M_DIM * K_DIM);          //  8 MiB
  unsigned short* Sbf = (unsigned short*)(ws + (size_t)M_DIM * K_DIM
                                             + (size_t)N_PAD * K_DIM);         // 16 MiB

  void* args[] = {(void*)&ys, (void*)&alphas, (void*)&repro, (void*)&b0,
                  (void*)&b1, (void*)&W8, (void*)&BT8, (void*)&Sbf, (void*)&out};
  hipError_t e = hipLaunchCooperativeKernel((const void*)k_fused, dim3(512),
                                            dim3(512), args, 0, stream);
  if (e != hipSuccess) {
    k_prep2<<<512, 512, 0, stream>>>(ys, alphas, repro, W8, BT8, Sbf);
    k_gemm2<<<512, 512, 0, stream>>>(W8, BT8, Sbf, b0, b1, out);
  }
}

// Round 6
// 253.918 us; speedup vs baseline: 1.7208x; 1.7208x over previous
//
#include <hip/hip_runtime.h>
#include <stdint.h>

#define M_DIM 4096
#define T_DIM 2048
#define N_OUT 2024
#define N_PAD 2048
#define WIN   25
#define K_DIM 4096

typedef float f32x4 __attribute__((ext_vector_type(4)));

__device__ __forceinline__ unsigned short f2bf(float x) {
  unsigned u = __float_as_uint(x);
  u += 0x7FFF + ((u >> 16) & 1);           // round-to-nearest-even
  return (unsigned short)(u >> 16);
}
__device__ __forceinline__ float bf2f(unsigned short h) {
  return __uint_as_float(((unsigned)h) << 16);
}

__device__ __forceinline__ void gl2lds16(const void* g, void* l) {
  // 16B-wide async global->LDS; HW dest = wave-uniform base + lane*16
  __builtin_amdgcn_global_load_lds(
      (const __attribute__((address_space(1))) unsigned int*)g,
      (__attribute__((address_space(3))) unsigned int*)l, 16, 0, 0);
}

// pack 4 floats -> 4 e4m3 bytes (one dword)
__device__ __forceinline__ int pk_fp8x4(float a, float b, float c, float d) {
  int w = __builtin_amdgcn_cvt_pk_fp8_f32(a, b, 0, false);
  w = __builtin_amdgcn_cvt_pk_fp8_f32(c, d, w, true);
  return w;
}

// ---------- Kernel 1: W8 = e4m3(sigmoid(alphas)), diagonal -> 0 ----------
// R0 version verbatim (coalesced float4 reads, uint2 writes).
__global__ __launch_bounds__(256) void k_wcast(const float* __restrict__ alphas,
                                               unsigned char* __restrict__ W8) {
  size_t i8 = ((size_t)blockIdx.x * 256 + threadIdx.x) * 8;
  const float4 v0 = *(const float4*)(alphas + i8);
  const float4 v1 = *(const float4*)(alphas + i8 + 4);
  int row = (int)(i8 >> 12);
  int col = (int)(i8 & 4095);
  float a[8] = {v0.x, v0.y, v0.z, v0.w, v1.x, v1.y, v1.z, v1.w};
  float w[8];
#pragma unroll
  for (int j = 0; j < 8; ++j)
    w[j] = (row == col + j) ? 0.f : 1.f / (1.f + __expf(-a[j]));
  int p0 = pk_fp8x4(w[0], w[1], w[2], w[3]);
  int p1 = pk_fp8x4(w[4], w[5], w[6], w[7]);
  *(uint2*)(W8 + i8) = uint2{(unsigned)p0, (unsigned)p1};
}

// ---------- Kernel 2: merged conv + transpose (ys read ONCE) ----------
// R13: block = 32 ys-rows x 280 cols staged in LDS once. From the same
// panel: (a) Sbf = bf16(softplus(conv)) — register sliding window, 32
// outputs/thread, k-order identical to R0 -> bitwise-identical Sbf;
// (b) BT8[n][k] = e4m3(ys[k][n+24]) for n in [c0,c0+256), k in [m0,m0+32).
// Saves the second 32 MB ys read and 34816 micro-block launches.
// Own kernel, own register budget (R12 lesson: no shared launch bounds).
__global__ __launch_bounds__(256) void k_convT(const float* __restrict__ ys,
                                               const float* __restrict__ repro,
                                               unsigned short* __restrict__ Sbf,
                                               unsigned char* __restrict__ BT8) {
  __shared__ float sy[32][284];   // 280 used + pad
  __shared__ float sr[32][26];
  const int tid = threadIdx.x;
  const int c0 = blockIdx.x * 256;   // 0..7 -> col chunk
  const int m0 = blockIdx.y * 32;    // 0..127 -> row chunk

  // stage ys[m0:m0+32][c0:c0+280) (zero past T_DIM); coalesced float4
  for (int slot = tid; slot < 32 * 70; slot += 256) {
    int r = slot / 70, f = slot % 70;
    int c = c0 + f * 4;              // 4-aligned; c<T_DIM => c+3<T_DIM
    float4 v = (c < T_DIM) ? *(const float4*)(ys + (size_t)(m0 + r) * T_DIM + c)
                           : float4{0.f, 0.f, 0.f, 0.f};
    sy[r][f * 4 + 0] = v.x; sy[r][f * 4 + 1] = v.y;
    sy[r][f * 4 + 2] = v.z; sy[r][f * 4 + 3] = v.w;
  }
  for (int slot = tid; slot < 32 * WIN; slot += 256) {
    int r = slot / WIN, k = slot % WIN;
    sr[r][k] = repro[(m0 + r) * WIN + k];
  }
  __syncthreads();

  // ---- conv: thread -> (row r = tid>>3, col group g = tid&7, 32 cols) ----
  {
    const int r = tid >> 3;
    const int cbase = (tid & 7) * 32;
    float y[56];
#pragma unroll
    for (int i = 0; i < 56; ++i) y[i] = sy[r][cbase + i];
    float rv[WIN];
#pragma unroll
    for (int k = 0; k < WIN; ++k) rv[k] = sr[r][k];
    unsigned pk[16];
#pragma unroll
    for (int jj = 0; jj < 32; ++jj) {
      float z = 0.f;
#pragma unroll
      for (int k = 0; k < WIN; ++k) z += y[jj + k] * rv[k];   // same k-order as R0
      float sp = fmaxf(z, 0.f) + log1pf(__expf(-fabsf(z)));
      int gj = c0 + cbase + jj;
      unsigned short h = (gj < N_OUT) ? f2bf(sp) : (unsigned short)0;
      if (jj & 1) pk[jj >> 1] |= ((unsigned)h) << 16;
      else        pk[jj >> 1]  = (unsigned)h;
    }
    unsigned short* dst = Sbf + (size_t)(m0 + r) * N_PAD + c0 + cbase;
    *(uint4*)(dst)      = *(const uint4*)(pk + 0);
    *(uint4*)(dst + 8)  = *(const uint4*)(pk + 4);
    *(uint4*)(dst + 16) = *(const uint4*)(pk + 8);
    *(uint4*)(dst + 24) = *(const uint4*)(pk + 12);
  }

  // ---- BT8: thread -> n = c0+tid; reads LDS col tid+24 (conflict-free) ----
  {
    const int n = c0 + tid;
    const bool ok = (n < N_OUT);
    unsigned w[8];
#pragma unroll
    for (int i = 0; i < 8; ++i) {
      float a0 = ok ? sy[4 * i + 0][tid + 24] : 0.f;
      float a1 = ok ? sy[4 * i + 1][tid + 24] : 0.f;
      float a2 = ok ? sy[4 * i + 2][tid + 24] : 0.f;
      float a3 = ok ? sy[4 * i + 3][tid + 24] : 0.f;
      w[i] = (unsigned)pk_fp8x4(a0, a1, a2, a3);
    }
    unsigned char* dst = BT8 + (size_t)n * K_DIM + m0;
    *(uint4*)(dst)      = uint4{w[0], w[1], w[2], w[3]};
    *(uint4*)(dst + 16) = uint4{w[4], w[5], w[6], w[7]};
  }
}

// ---------- GEMM: C = W8 @ BT8^T (fp8 MFMA), out = beta * (S + C) ----------
// R9 body verbatim — best measured (86.4 us, MfmaUtil 32%): 512 threads,
// 8 waves, wave = 64x32 out, 4-buffer depth-3 counted vmcnt(6), raw
// s_barrier, XOR chunk swizzle, XCD-bijective block swizzle.
__global__ __launch_bounds__(512, 4) void k_gemm(const unsigned char* __restrict__ W8,
                                                 const unsigned char* __restrict__ BT8,
                                                 const unsigned short* __restrict__ Sbf,
                                                 const float* __restrict__ b0,
                                                 const float* __restrict__ b1,
                                                 float* __restrict__ out) {
  __shared__ __align__(64) unsigned char lA[4][128 * 64];   // 32 KB
  __shared__ __align__(64) unsigned char lB[4][128 * 64];   // 32 KB
  const int tid  = threadIdx.x;
  const int wave = tid >> 6;          // 0..7
  const int lane = tid & 63;
  const int wm = wave >> 2;           // 0..1 : 64-row slice
  const int wn = wave & 3;            // 0..3 : 32-col slice
  const int m16  = lane & 15;
  const int quad = lane >> 4;

  // XCD-aware bijective swizzle (512%8==0): each XCD gets 64 consecutive
  // tiles = 4 full M-rows -> A-panels L2-local.
  const int fid  = blockIdx.y * gridDim.x + blockIdx.x;   // 0..511
  const int swz  = (fid & 7) * 64 + (fid >> 3);
  const int tileN = (swz & 15) * 128;
  const int tileM = (swz >> 4) * 128;

  const int key  = (m16 >> 1) & 3;
  const int sub  = (quad & 1) * 8;
  const int rowA = (wm * 64 + m16) * 64;
  const int rowB = (wn * 32 + m16) * 64;
  int hOf[2];
#pragma unroll
  for (int h = 0; h < 2; ++h)
    hOf[h] = (((2 * h + (quad >> 1)) ^ key) << 4) + sub;

  const int o = wave * 1024 + lane * 16;   // 0..8191
  const int r = o >> 6;                    // LDS row 0..127
  const int s = (o >> 4) & 3;              // LDS chunk slot
  const int q = s ^ ((r >> 1) & 3);        // logical (global) chunk
  const unsigned char* gA = W8  + (size_t)(tileM + r) * K_DIM + q * 16;
  const unsigned char* gB = BT8 + (size_t)(tileN + r) * K_DIM + q * 16;
  const int ldsOff = wave * 1024;          // wave-uniform base

  f32x4 acc[4][2];
#pragma unroll
  for (int i = 0; i < 4; ++i)
#pragma unroll
    for (int j = 0; j < 2; ++j) acc[i][j] = f32x4{0.f, 0.f, 0.f, 0.f};

  auto stage = [&](int buf, int kt_) {
    const size_t kb_ = (size_t)kt_ * 64;
    gl2lds16(gA + kb_, &lA[buf][ldsOff]);
    gl2lds16(gB + kb_, &lB[buf][ldsOff]);
  };
  auto compute = [&](int buf) {
#pragma unroll
    for (int h = 0; h < 2; ++h) {
      long long aF[4], bF[2];
#pragma unroll
      for (int i = 0; i < 4; ++i)
        aF[i] = *(const long long*)&lA[buf][rowA + i * 1024 + hOf[h]];
#pragma unroll
      for (int j = 0; j < 2; ++j)
        bF[j] = *(const long long*)&lB[buf][rowB + j * 1024 + hOf[h]];
#pragma unroll
      for (int i = 0; i < 4; ++i)
#pragma unroll
        for (int j = 0; j < 2; ++j)
          acc[i][j] = __builtin_amdgcn_mfma_f32_16x16x32_fp8_fp8(
              aF[i], bF[j], acc[i][j], 0, 0, 0);
    }
  };

  stage(0, 0);
  stage(1, 1);
  stage(2, 2);

#pragma unroll 1
  for (int kt = 0; kt < K_DIM / 64; kt += 4) {
    stage(3, kt + 3);
    asm volatile("s_waitcnt vmcnt(6)" ::: "memory");
    __builtin_amdgcn_s_barrier();
    asm volatile("" ::: "memory");
    compute(0);
    __builtin_amdgcn_s_barrier();
    asm volatile("" ::: "memory");

    if (kt + 4 < K_DIM / 64) {
      stage(0, kt + 4);
      asm volatile("s_waitcnt vmcnt(6)" ::: "memory");
    } else {
      asm volatile("s_waitcnt vmcnt(4)" ::: "memory");
    }
    __builtin_amdgcn_s_barrier();
    asm volatile("" ::: "memory");
    compute(1);
    __builtin_amdgcn_s_barrier();
    asm volatile("" ::: "memory");

    if (kt + 5 < K_DIM / 64) {
      stage(1, kt + 5);
      asm volatile("s_waitcnt vmcnt(6)" ::: "memory");
    } else {
      asm volatile("s_waitcnt vmcnt(2)" ::: "memory");
    }
    __builtin_amdgcn_s_barrier();
    asm volatile("" ::: "memory");
    compute(2);
    __builtin_amdgcn_s_barrier();
    asm volatile("" ::: "memory");

    if (kt + 6 < K_DIM / 64) {
      stage(2, kt + 6);
      asm volatile("s_waitcnt vmcnt(6)" ::: "memory");
    } else {
      asm volatile("s_waitcnt vmcnt(0)" ::: "memory");
    }
    __builtin_amdgcn_s_barrier();
    asm volatile("" ::: "memory");
    compute(3);
    __builtin_amdgcn_s_barrier();
    asm volatile("" ::: "memory");
  }

  // Epilogue: out[gm][gn] = softplus(b0+b1*(gn+25)) * (S[gm][gn] + C)
#pragma unroll
  for (int j = 0; j < 2; ++j) {
    int gn = tileN + wn * 32 + j * 16 + m16;
    if (gn >= N_OUT) continue;
    float tval = (float)(gn + WIN);
#pragma unroll
    for (int i = 0; i < 4; ++i) {
#pragma unroll
      for (int r2 = 0; r2 < 4; ++r2) {
        int gm = tileM + wm * 64 + i * 16 + quad * 4 + r2;
        float x = b0[gm] + b1[gm] * tval;
        float beta = fmaxf(x, 0.f) + log1pf(__expf(-fabsf(x)));
        float sv = bf2f(Sbf[(size_t)gm * N_PAD + gn]);
        out[(size_t)gm * N_OUT + gn] = beta * (sv + acc[i][j][r2]);
      }
    }
  }
}

extern "C" void kernel_launch(void* const* d_in, const int* in_sizes, int n_in,
                              void* d_out, int out_size, void* d_ws, size_t ws_size,
                              hipStream_t stream) {
  const float* ys     = (const float*)d_in[0];
  const float* alphas = (const float*)d_in[1];
  const float* repro  = (const float*)d_in[2];
  const float* b0     = (const float*)d_in[3];
  const float* b1     = (const float*)d_in[4];
  float* out = (float*)d_out;

  char* ws = (char*)d_ws;
  unsigned char*  W8  = (unsigned char*)ws;                                    // 16 MiB
  unsigned char*  BT8 = (unsigned char*)(ws + (size_t)M_DIM * K_DIM);          //  8 MiB
  unsigned short* Sbf = (unsigned short*)(ws + (size_t)M_DIM * K_DIM
                                             + (size_t)N_PAD * K_DIM);         // 16 MiB

  k_wcast<<<(M_DIM * (size_t)K_DIM) / 8 / 256, 256, 0, stream>>>(alphas, W8);
  k_convT<<<dim3(T_DIM / 256, M_DIM / 32), 256, 0, stream>>>(ys, repro, Sbf, BT8);
  k_gemm<<<dim3(N_PAD / 128, M_DIM / 128), 512, 0, stream>>>(W8, BT8, Sbf,
                                                             b0, b1, out);
}